// Round 15
// baseline (232.865 us; speedup 1.0000x reference)
//
#include <hip/hip_runtime.h>
#include <cmath>

// BlockwiseEarlyExitMamba: output depends only on feat[:,31,:] -> compute T=32 tokens.
// r15 = r14 (XCD-local placement) + k_A GEMM re-tiled to r2-style 4x4 micro-tile
// (16 FMA per 2 ds_read_b128 instead of 4 FMA per 2 LDS instrs -> 4x fewer LDS ops).
#define TT 32
#define NTOK 512   // BATCH*TT
#define DM 256
#define DI 512

typedef float vf4 __attribute__((ext_vector_type(4)));

__device__ __forceinline__ float silu_(float x){ return x / (1.f + __expf(-x)); }

#define FMA16() do { \
  acc[0][0] += xv.x*wv.x; acc[0][1] += xv.x*wv.y; acc[0][2] += xv.x*wv.z; acc[0][3] += xv.x*wv.w; \
  acc[1][0] += xv.y*wv.x; acc[1][1] += xv.y*wv.y; acc[1][2] += xv.y*wv.z; acc[1][3] += xv.y*wv.w; \
  acc[2][0] += xv.z*wv.x; acc[2][1] += xv.z*wv.y; acc[2][2] += xv.z*wv.z; acc[2][3] += xv.z*wv.w; \
  acc[3][0] += xv.w*wv.x; acc[3][1] += xv.w*wv.y; acc[3][2] += xv.w*wv.z; acc[3][3] += xv.w*wv.w; \
} while(0)

// ---------- frontend: embed -> fusion GEMM (K=136) -> raw s0 (verified r2) ---
// grid dim3(16 b, 4 nt)
__global__ __launch_bounds__(128)
void k_front(const float* __restrict__ x,
             const float* __restrict__ ep, const float* __restrict__ ef,
             const float* __restrict__ ed,
             const float* __restrict__ plw, const float* __restrict__ plb,
             const float* __restrict__ piw, const float* __restrict__ pib,
             const float* __restrict__ fw,  const float* __restrict__ fb,
             float* __restrict__ s0)
{
  __shared__ float Xs[136*36];
  __shared__ float Ws[136*68];
  int bb = blockIdx.x;
  int n0 = blockIdx.y*64;
  int tid = threadIdx.x;
  for (int r = 0; r < 34; ++r){
    int idx = r*128 + tid;
    int t = idx & 31, j = idx >> 5;
    const float* xr = x + ((size_t)(bb*1024 + t))*5;
    float v;
    if      (j <  32){ int i = __float2int_rz(xr[0]); i = min(max(i,0),255); v = ep[i*32 + j]; }
    else if (j <  64){ v = xr[1]*plw[j-32] + plb[j-32]; }
    else if (j <  96){ int i = __float2int_rz(xr[2]); i = min(max(i,0),63);  v = ef[i*32 + (j-64)]; }
    else if (j < 128){ v = xr[3]*piw[j-96] + pib[j-96]; }
    else             { int i = __float2int_rz(xr[4]); i = min(max(i,0),1);   v = ed[i*8 + (j-128)]; }
    Xs[j*36 + t] = v;
  }
  {
    int c = tid >> 1, jh = tid & 1;
    const float4* src = (const float4*)(fw + (size_t)(n0 + c)*136 + jh*68);
    #pragma unroll
    for (int q = 0; q < 17; ++q){
      float4 v = src[q];
      int j = jh*68 + q*4;
      Ws[(j+0)*68 + c] = v.x; Ws[(j+1)*68 + c] = v.y;
      Ws[(j+2)*68 + c] = v.z; Ws[(j+3)*68 + c] = v.w;
    }
  }
  __syncthreads();
  int my = tid >> 4, nx = tid & 15;
  float acc[4][4] = {};
  #pragma unroll 4
  for (int k = 0; k < 136; ++k){
    float4 xv = *(const float4*)&Xs[k*36 + my*4];
    float4 wv = *(const float4*)&Ws[k*68 + nx*4];
    FMA16();
  }
  #pragma unroll
  for (int i = 0; i < 4; ++i){
    int t = my*4 + i;
    float4 o;
    o.x = acc[i][0] + fb[n0 + nx*4 + 0];
    o.y = acc[i][1] + fb[n0 + nx*4 + 1];
    o.z = acc[i][2] + fb[n0 + nx*4 + 2];
    o.w = acc[i][3] + fb[n0 + nx*4 + 3];
    *(float4*)&s0[(size_t)(bb*32 + t)*DM + n0 + nx*4] = o;
  }
}

// ---------- k_A: LN prologue (8 parts) + in_proj GEMM (4x4) + conv/silu + xpp
// grid dim3(16 b, 16 nt), 256 thr, dyn LDS 71680B. nt<8: x-channels, nt>=8: z.
__global__ __launch_bounds__(256)
void k_A(const float* __restrict__ wip, const float* __restrict__ cwl,
         const float* __restrict__ cbl, const float* __restrict__ xpl,
         const float* __restrict__ g, const float* __restrict__ bb,
         const float* __restrict__ parts, int resid,
         const float* __restrict__ featIn, float* __restrict__ featOut,
         float* __restrict__ xc, float* __restrict__ zs, float* __restrict__ pxp)
{
  extern __shared__ float lds[];
  float* featT = lds;          // [256][36] 9216
  float* Ws    = lds + 9216;   // [64][68] 4352 (LN-red region first)
  float* sxz   = lds + 13568;  // [32][68] 2176
  float* xcl   = lds + 15744;  // [32][68] 2176   total 17920 floats = 71680 B
  int tid = threadIdx.x;
  int b = blockIdx.x, nt = blockIdx.y;   // XCD-local: linear%8 == b%8
  int n0 = nt*64;

  { // ---- LN prologue: sum 8 parts (+featIn) or single s0; LN -> featT ----
    int t = tid & 31, ci = tid >> 5;       // ci 0..7 -> 32 channels each
    size_t base = (size_t)(b*32 + t)*DM + ci*32;
    float v[32];
    {
      const float4* p0 = (const float4*)(parts + base);
      #pragma unroll
      for (int q = 0; q < 8; ++q){
        float4 u = p0[q];
        v[q*4+0]=u.x; v[q*4+1]=u.y; v[q*4+2]=u.z; v[q*4+3]=u.w;
      }
    }
    if (resid){
      #pragma unroll
      for (int p2 = 1; p2 < 8; ++p2){
        const float4* pq = (const float4*)(parts + (size_t)p2*NTOK*DM + base);
        #pragma unroll
        for (int q = 0; q < 8; ++q){
          float4 u = pq[q];
          v[q*4+0]+=u.x; v[q*4+1]+=u.y; v[q*4+2]+=u.z; v[q*4+3]+=u.w;
        }
      }
      const float4* pf = (const float4*)(featIn + base);
      #pragma unroll
      for (int q = 0; q < 8; ++q){
        float4 u = pf[q];
        v[q*4+0]+=u.x; v[q*4+1]+=u.y; v[q*4+2]+=u.z; v[q*4+3]+=u.w;
      }
    }
    float s = 0.f, sq = 0.f;
    #pragma unroll
    for (int j = 0; j < 32; ++j){ s += v[j]; sq += v[j]*v[j]; }
    float* redS = Ws; float* redQ = Ws + 288;   // [32][9] each
    redS[t*9 + ci] = s; redQ[t*9 + ci] = sq;
    __syncthreads();
    float S = 0.f, Q = 0.f;
    #pragma unroll
    for (int k2 = 0; k2 < 8; ++k2){ S += redS[t*9+k2]; Q += redQ[t*9+k2]; }
    float mu = S*(1.f/256.f), var = Q*(1.f/256.f) - mu*mu;
    float r = rsqrtf(var + 1e-5f);
    #pragma unroll
    for (int j = 0; j < 32; ++j){
      int c = ci*32 + j;
      v[j] = (v[j]-mu)*r*g[c] + bb[c];
      featT[c*36 + t] = v[j];
    }
    if (nt == 0){
      #pragma unroll
      for (int q = 0; q < 8; ++q){
        float4 o = {v[q*4+0], v[q*4+1], v[q*4+2], v[q*4+3]};
        *(float4*)&featOut[base + q*4] = o;
      }
    }
  }

  // ---- in_proj GEMM: r2-style 4x4 micro-tile on tid<128 (2 waves); all stage
  int my = tid >> 4, nx = tid & 15;      // valid for tid<128
  float acc[4][4] = {};
  for (int kc = 0; kc < 4; ++kc){
    __syncthreads();
    { // stage W chunk [64 k][64 c] with all 256 threads
      int c = tid >> 2, kq = tid & 3;
      const float4* src = (const float4*)(wip + (size_t)(n0+c)*DM + kc*64 + kq*16);
      #pragma unroll
      for (int q = 0; q < 4; ++q){
        float4 u = src[q];
        int k = kq*16 + q*4;
        Ws[(k+0)*68 + c] = u.x; Ws[(k+1)*68 + c] = u.y;
        Ws[(k+2)*68 + c] = u.z; Ws[(k+3)*68 + c] = u.w;
      }
    }
    __syncthreads();
    if (tid < 128){
      #pragma unroll 4
      for (int kk = 0; kk < 64; ++kk){
        float4 xv = *(const float4*)&featT[(kc*64 + kk)*36 + my*4];
        float4 wv = *(const float4*)&Ws[kk*68 + nx*4];
        FMA16();
      }
    }
  }
  __syncthreads();
  if (tid < 128){
    #pragma unroll
    for (int i = 0; i < 4; ++i){
      float4 o = {acc[i][0], acc[i][1], acc[i][2], acc[i][3]};
      *(float4*)&sxz[(my*4 + i)*68 + nx*4] = o;
    }
  }
  __syncthreads();

  { // conv+silu (x) / silu (z); 8 ch/thread; coalesced float4 global stores
    int t = tid >> 3, c8 = (tid & 7)*8;
    float rr[8];
    if (n0 < 512){
      #pragma unroll
      for (int j = 0; j < 8; ++j){
        int c = c8 + j, d = n0 + c;
        float4 k4 = *(const float4*)(cwl + (size_t)d*4);
        float a = cbl[d];
        if (t >= 3) a += k4.x*sxz[(t-3)*68 + c];
        if (t >= 2) a += k4.y*sxz[(t-2)*68 + c];
        if (t >= 1) a += k4.z*sxz[(t-1)*68 + c];
        a += k4.w*sxz[t*68 + c];
        rr[j] = silu_(a);
        xcl[t*68 + c] = rr[j];
      }
      float4 o0 = {rr[0], rr[1], rr[2], rr[3]};
      float4 o1 = {rr[4], rr[5], rr[6], rr[7]};
      *(float4*)&xc[(size_t)(b*32 + t)*DI + n0 + c8]     = o0;
      *(float4*)&xc[(size_t)(b*32 + t)*DI + n0 + c8 + 4] = o1;
    } else {
      #pragma unroll
      for (int j = 0; j < 8; ++j) rr[j] = silu_(sxz[t*68 + c8 + j]);
      float4 o0 = {rr[0], rr[1], rr[2], rr[3]};
      float4 o1 = {rr[4], rr[5], rr[6], rr[7]};
      *(float4*)&zs[(size_t)(b*32 + t)*DI + (n0-512) + c8]     = o0;
      *(float4*)&zs[(size_t)(b*32 + t)*DI + (n0-512) + c8 + 4] = o1;
    }
  }
  if (n0 < 512){
    __syncthreads();
    // x_proj partials over this block's 64 dims: 4 waves x 12 ch
    int w = tid >> 6, ln = tid & 63;
    int tt = ln & 31, half = ln >> 5;
    #pragma unroll
    for (int j = 0; j < 12; ++j){
      int c = w*12 + j;
      const float* wr = xpl + (size_t)c*DI + n0 + half*32;
      const float* xr = xcl + tt*68 + half*32;
      float pa = 0.f;
      #pragma unroll 8
      for (int q = 0; q < 32; ++q) pa += wr[q]*xr[q];
      pa += __shfl_xor(pa, 32, 64);
      if (half == 0) pxp[((size_t)(b*8 + nt)*48 + c)*32 + tt] = pa;
    }
  }
}

// ---------- k_sc: xp-reduce + dt + scan + gate + out_proj -> parts[8] --------
// grid dim3(16 b, 8 ds of 64 d), 512 thr, static LDS ~75KB  (verified r14)
__global__ __launch_bounds__(512)
void k_sc(const float* __restrict__ pxp,
          const float* __restrict__ dtwl, const float* __restrict__ dtbl,
          const float* __restrict__ alogl, const float* __restrict__ dprl,
          const float* __restrict__ opwl,
          const float* __restrict__ xc, const float* __restrict__ zs,
          float* __restrict__ parts)
{
  __shared__ float sdtr[32*18], sB[32*18], sC[32*18];
  __shared__ float sdt[32*68], sxv[32*68], szz[32*68];
  __shared__ float ygT[64*36];
  __shared__ float Wop[32*260];
  int tid = threadIdx.x;
  int b = blockIdx.x, ds = blockIdx.y;   // XCD-local: linear%8 == b%8
  int d0 = ds*64;

  #pragma unroll
  for (int r = 0; r < 3; ++r){
    int o = r*512 + tid;
    int c = o >> 5, t = o & 31;
    size_t p0 = ((size_t)(b*8)*48 + c)*32 + t;
    float v = 0.f;
    #pragma unroll
    for (int nb = 0; nb < 8; ++nb) v += pxp[p0 + (size_t)nb*1536];
    if      (c < 16) sdtr[t*18 + c] = v;
    else if (c < 32) sB[t*18 + (c-16)] = v;
    else             sC[t*18 + (c-32)] = v;
  }
  {
    int t = tid >> 4, dq = (tid & 15)*4;
    size_t base = (size_t)(b*32 + t)*DI + d0 + dq;
    *(float4*)&sxv[t*68 + dq] = *(const float4*)&xc[base];
    *(float4*)&szz[t*68 + dq] = *(const float4*)&zs[base];
  }
  __syncthreads();
  {
    int dl = tid & 63, tg2 = tid >> 6;
    int d = d0 + dl;
    const float4* dwr = (const float4*)(dtwl + (size_t)d*16);
    float4 w0 = dwr[0], w1 = dwr[1], w2 = dwr[2], w3 = dwr[3];
    float bsv = dtbl[d];
    #pragma unroll
    for (int tt2 = 0; tt2 < 4; ++tt2){
      int t = tg2*4 + tt2;
      const float* sr = &sdtr[t*18];
      float a = bsv;
      a += w0.x*sr[0] + w0.y*sr[1] + w0.z*sr[2] + w0.w*sr[3];
      a += w1.x*sr[4] + w1.y*sr[5] + w1.z*sr[6] + w1.w*sr[7];
      a += w2.x*sr[8] + w2.y*sr[9] + w2.z*sr[10]+ w2.w*sr[11];
      a += w3.x*sr[12]+ w3.y*sr[13]+ w3.z*sr[14]+ w3.w*sr[15];
      sdt[t*68 + dl] = fmaxf(a, 0.f) + log1pf(expf(-fabsf(a)));
    }
  }
  __syncthreads();
  {
    int dd = tid >> 3, ng = tid & 7;
    int d = d0 + dd;
    int n0i = ng*2;
    float A0 = -expf(alogl[(size_t)d*16 + n0i]);
    float A1 = -expf(alogl[(size_t)d*16 + n0i + 1]);
    float Dp = dprl[d];
    float h0 = 0.f, h1 = 0.f;
    #pragma unroll 4
    for (int t = 0; t < TT; ++t){
      float dt = sdt[t*68 + dd];
      float xv = sxv[t*68 + dd];
      float dx = dt*xv;
      h0 = __expf(dt*A0)*h0 + dx*sB[t*18 + n0i];
      h1 = __expf(dt*A1)*h1 + dx*sB[t*18 + n0i + 1];
      float yv = h0*sC[t*18 + n0i] + h1*sC[t*18 + n0i + 1];
      yv += __shfl_xor(yv, 1, 64);
      yv += __shfl_xor(yv, 2, 64);
      yv += __shfl_xor(yv, 4, 64);
      if (ng == 0) ygT[dd*36 + t] = (yv + Dp*xv) * szz[t*68 + dd];
    }
  }
  int cW = tid >> 1, khW = tid & 1;
  int w = tid >> 6, cq = (tid & 63)*4;
  float acc[4][4] = {};
  for (int kc = 0; kc < 2; ++kc){
    __syncthreads();
    {
      const float4* src = (const float4*)(opwl + (size_t)cW*DI + d0 + kc*32 + khW*16);
      #pragma unroll
      for (int q = 0; q < 4; ++q){
        float4 u = src[q];
        int k = khW*16 + q*4;
        Wop[(k+0)*260 + cW] = u.x; Wop[(k+1)*260 + cW] = u.y;
        Wop[(k+2)*260 + cW] = u.z; Wop[(k+3)*260 + cW] = u.w;
      }
    }
    __syncthreads();
    #pragma unroll 4
    for (int k = 0; k < 32; ++k){
      vf4 xv = *(const vf4*)&ygT[(kc*32 + k)*36 + w*4];
      vf4 wv = *(const vf4*)&Wop[k*260 + cq];
      #pragma unroll
      for (int i = 0; i < 4; ++i){
        #pragma unroll
        for (int j = 0; j < 4; ++j) acc[i][j] += xv[i]*wv[j];
      }
    }
  }
  float* dst = parts + (size_t)ds*NTOK*DM;
  #pragma unroll
  for (int i = 0; i < 4; ++i){
    float4 o = {acc[i][0], acc[i][1], acc[i][2], acc[i][3]};
    *(float4*)&dst[(size_t)(b*32 + w*4 + i)*DM + cq] = o;
  }
}

// ---------- CLS: final residual+LN (token 31, 8 parts) + classifier ----------
__global__ __launch_bounds__(128)
void k_cls(const float* __restrict__ feat3, const float* __restrict__ parts,
           const float* __restrict__ ng, const float* __restrict__ nb,
           const float* __restrict__ w1, const float* __restrict__ b1,
           const float* __restrict__ w2, const float* __restrict__ b2,
           float* __restrict__ out)
{
  __shared__ float h[256];
  __shared__ float h1[128];
  int b = blockIdx.x, tid = threadIdx.x;
  if (tid < 64){
    int c4 = tid*4;
    size_t base = (size_t)(b*32 + 31)*DM + c4;
    float4 v = *(const float4*)&feat3[base];
    #pragma unroll
    for (int q = 0; q < 8; ++q){
      float4 u = *(const float4*)&parts[(size_t)q*NTOK*DM + base];
      v.x += u.x; v.y += u.y; v.z += u.z; v.w += u.w;
    }
    float sm = v.x+v.y+v.z+v.w;
    float sq = v.x*v.x+v.y*v.y+v.z*v.z+v.w*v.w;
    #pragma unroll
    for (int o = 1; o < 64; o <<= 1){ sm += __shfl_xor(sm, o, 64); sq += __shfl_xor(sq, o, 64); }
    float mu = sm*(1.f/256.f), var = sq*(1.f/256.f) - mu*mu;
    float r = rsqrtf(var + 1e-5f);
    h[c4+0] = (v.x-mu)*r*ng[c4+0] + nb[c4+0];
    h[c4+1] = (v.y-mu)*r*ng[c4+1] + nb[c4+1];
    h[c4+2] = (v.z-mu)*r*ng[c4+2] + nb[c4+2];
    h[c4+3] = (v.w-mu)*r*ng[c4+3] + nb[c4+3];
  }
  __syncthreads();
  {
    float a = b1[tid];
    const float* wr = w1 + (size_t)tid*256;
    #pragma unroll 8
    for (int j = 0; j < 256; ++j) a += h[j]*wr[j];
    h1[tid] = fmaxf(a, 0.f);
  }
  __syncthreads();
  if (tid < 2){
    float a2 = b2[tid];
    const float* wr2 = w2 + (size_t)tid*128;
    #pragma unroll 8
    for (int j = 0; j < 128; ++j) a2 += h1[j]*wr2[j];
    out[b*2 + tid] = a2;
  }
}

extern "C" void kernel_launch(void* const* d_in, const int* in_sizes, int n_in,
                              void* d_out, int out_size, void* d_ws, size_t ws_size,
                              hipStream_t stream)
{
  const float* x   = (const float*)d_in[0];
  const float* ep  = (const float*)d_in[1];
  const float* ef  = (const float*)d_in[2];
  const float* ed  = (const float*)d_in[3];
  const float* plw = (const float*)d_in[4];
  const float* plb = (const float*)d_in[5];
  const float* piw = (const float*)d_in[6];
  const float* pib = (const float*)d_in[7];
  const float* fw  = (const float*)d_in[8];
  const float* fb  = (const float*)d_in[9];
  const float* tg  = (const float*)d_in[10];
  const float* tb  = (const float*)d_in[11];
  const float* ng  = (const float*)d_in[12];
  const float* nb  = (const float*)d_in[13];
  const float* ipw = (const float*)d_in[14];
  const float* cw  = (const float*)d_in[15];
  const float* cb  = (const float*)d_in[16];
  const float* xpw = (const float*)d_in[17];
  const float* dtw = (const float*)d_in[18];
  const float* dtb = (const float*)d_in[19];
  const float* alog= (const float*)d_in[20];
  const float* dpr = (const float*)d_in[21];
  const float* opw = (const float*)d_in[22];
  const float* w1  = (const float*)d_in[23];
  const float* b1  = (const float*)d_in[24];
  const float* w2  = (const float*)d_in[25];
  const float* b2  = (const float*)d_in[26];
  (void)in_sizes; (void)n_in; (void)out_size; (void)ws_size;

  float* ws    = (float*)d_ws;
  float* s0    = ws;                       // 131072
  float* fb0   = s0  + NTOK*DM;            // 131072
  float* fb1   = fb0 + NTOK*DM;            // 131072
  float* parts = fb1 + NTOK*DM;            // 8*131072
  float* pxp   = parts + 8*NTOK*DM;        // 196608
  float* xc    = pxp + 196608;             // 262144
  float* zs    = xc  + NTOK*DI;            // 262144
  float* fbuf[2] = {fb0, fb1};

  k_front<<<dim3(16,4),128,0,stream>>>(x, ep,ef,ed, plw,plb,piw,pib, fw,fb, s0);

  for (int ly = 0; ly < 4; ++ly){
    const float* gg = ly ? ng : tg;
    const float* gb = ly ? nb : tb;
    const float* pin = ly ? parts : s0;
    const float* fin = ly ? fbuf[(ly+1)&1] : nullptr;
    k_A<<<dim3(16,16),256,71680,stream>>>(ipw + (size_t)ly*262144,
                                          cw + (size_t)ly*2048, cb + (size_t)ly*512,
                                          xpw + (size_t)ly*24576,
                                          gg, gb, pin, ly ? 1 : 0, fin,
                                          fbuf[ly&1], xc, zs, pxp);
    k_sc<<<dim3(16,8),512,0,stream>>>(pxp,
                                      dtw + (size_t)ly*8192, dtb + (size_t)ly*512,
                                      alog + (size_t)ly*8192, dpr + (size_t)ly*512,
                                      opw + (size_t)ly*131072,
                                      xc, zs, parts);
  }
  k_cls<<<16,128,0,stream>>>(fbuf[1], parts, ng, nb, w1, b1, w2, b2, (float*)d_out);
}

// Round 16
// 194.733 us; speedup vs baseline: 1.1958x; 1.1958x over previous
//
#include <hip/hip_runtime.h>
#include <cmath>

// BlockwiseEarlyExitMamba: output depends only on feat[:,31,:] -> compute T=32 tokens.
// r16 = r14 (verified 195us) + k_A W-chunk-0 register prefetch (T14 async-stage split):
// issue the first in_proj weight chunk's loads at kernel entry, consume after LN.
#define TT 32
#define NTOK 512   // BATCH*TT
#define DM 256
#define DI 512

typedef float vf4 __attribute__((ext_vector_type(4)));

__device__ __forceinline__ float silu_(float x){ return x / (1.f + __expf(-x)); }

#define FMA16() do { \
  acc[0][0] += xv.x*wv.x; acc[0][1] += xv.x*wv.y; acc[0][2] += xv.x*wv.z; acc[0][3] += xv.x*wv.w; \
  acc[1][0] += xv.y*wv.x; acc[1][1] += xv.y*wv.y; acc[1][2] += xv.y*wv.z; acc[1][3] += xv.y*wv.w; \
  acc[2][0] += xv.z*wv.x; acc[2][1] += xv.z*wv.y; acc[2][2] += xv.z*wv.z; acc[2][3] += xv.z*wv.w; \
  acc[3][0] += xv.w*wv.x; acc[3][1] += xv.w*wv.y; acc[3][2] += xv.w*wv.z; acc[3][3] += xv.w*wv.w; \
} while(0)

// ---------- frontend: embed -> fusion GEMM (K=136) -> raw s0 (verified r2) ---
// grid dim3(16 b, 4 nt)
__global__ __launch_bounds__(128)
void k_front(const float* __restrict__ x,
             const float* __restrict__ ep, const float* __restrict__ ef,
             const float* __restrict__ ed,
             const float* __restrict__ plw, const float* __restrict__ plb,
             const float* __restrict__ piw, const float* __restrict__ pib,
             const float* __restrict__ fw,  const float* __restrict__ fb,
             float* __restrict__ s0)
{
  __shared__ float Xs[136*36];
  __shared__ float Ws[136*68];
  int bb = blockIdx.x;
  int n0 = blockIdx.y*64;
  int tid = threadIdx.x;
  for (int r = 0; r < 34; ++r){
    int idx = r*128 + tid;
    int t = idx & 31, j = idx >> 5;
    const float* xr = x + ((size_t)(bb*1024 + t))*5;
    float v;
    if      (j <  32){ int i = __float2int_rz(xr[0]); i = min(max(i,0),255); v = ep[i*32 + j]; }
    else if (j <  64){ v = xr[1]*plw[j-32] + plb[j-32]; }
    else if (j <  96){ int i = __float2int_rz(xr[2]); i = min(max(i,0),63);  v = ef[i*32 + (j-64)]; }
    else if (j < 128){ v = xr[3]*piw[j-96] + pib[j-96]; }
    else             { int i = __float2int_rz(xr[4]); i = min(max(i,0),1);   v = ed[i*8 + (j-128)]; }
    Xs[j*36 + t] = v;
  }
  {
    int c = tid >> 1, jh = tid & 1;
    const float4* src = (const float4*)(fw + (size_t)(n0 + c)*136 + jh*68);
    #pragma unroll
    for (int q = 0; q < 17; ++q){
      float4 v = src[q];
      int j = jh*68 + q*4;
      Ws[(j+0)*68 + c] = v.x; Ws[(j+1)*68 + c] = v.y;
      Ws[(j+2)*68 + c] = v.z; Ws[(j+3)*68 + c] = v.w;
    }
  }
  __syncthreads();
  int my = tid >> 4, nx = tid & 15;
  float acc[4][4] = {};
  #pragma unroll 4
  for (int k = 0; k < 136; ++k){
    float4 xv = *(const float4*)&Xs[k*36 + my*4];
    float4 wv = *(const float4*)&Ws[k*68 + nx*4];
    FMA16();
  }
  #pragma unroll
  for (int i = 0; i < 4; ++i){
    int t = my*4 + i;
    float4 o;
    o.x = acc[i][0] + fb[n0 + nx*4 + 0];
    o.y = acc[i][1] + fb[n0 + nx*4 + 1];
    o.z = acc[i][2] + fb[n0 + nx*4 + 2];
    o.w = acc[i][3] + fb[n0 + nx*4 + 3];
    *(float4*)&s0[(size_t)(bb*32 + t)*DM + n0 + nx*4] = o;
  }
}

// ---------- k_A: LN prologue (8 parts) + in_proj GEMM + conv/silu + xp-partials
// grid dim3(16 b, 16 nt), 512 thr, dyn LDS 70912B. nt<8: x-channels, nt>=8: z.
__global__ __launch_bounds__(512)
void k_A(const float* __restrict__ wip, const float* __restrict__ cwl,
         const float* __restrict__ cbl, const float* __restrict__ xpl,
         const float* __restrict__ g, const float* __restrict__ bb,
         const float* __restrict__ parts, int resid,
         const float* __restrict__ featIn, float* __restrict__ featOut,
         float* __restrict__ xc, float* __restrict__ zs, float* __restrict__ pxp)
{
  extern __shared__ float lds[];
  float* featT = lds;          // [256][36] 9216
  float* Ws    = lds + 9216;   // [64][68] 4352
  float* sxz   = lds + 13568;  // [32][65] 2080
  float* xcl   = lds + 15648;  // [32][65] 2080  (LN reduction scratch before conv)
  int tid = threadIdx.x;
  int b = blockIdx.x, nt = blockIdx.y;   // XCD-local: linear%8 == b%8
  int n0 = nt*64;

  // ---- T14 prefetch: issue W chunk-0 loads before anything else ----
  int cP = tid >> 3, khP = tid & 7;
  const float4* srcP = (const float4*)(wip + (size_t)(n0+cP)*DM + khP*8);
  float4 pW0 = srcP[0], pW1 = srcP[1];

  { // ---- LN prologue: sum 8 parts (+featIn) or single s0; LN -> featT ----
    int t = tid & 31, ci = tid >> 5;       // ci 0..15 -> 16 channels each
    size_t base = (size_t)(b*32 + t)*DM + ci*16;
    float v[16];
    {
      const float4* p0 = (const float4*)(parts + base);
      #pragma unroll
      for (int q = 0; q < 4; ++q){
        float4 u = p0[q];
        v[q*4+0]=u.x; v[q*4+1]=u.y; v[q*4+2]=u.z; v[q*4+3]=u.w;
      }
    }
    if (resid){
      #pragma unroll
      for (int p2 = 1; p2 < 8; ++p2){
        const float4* pq = (const float4*)(parts + (size_t)p2*NTOK*DM + base);
        #pragma unroll
        for (int q = 0; q < 4; ++q){
          float4 u = pq[q];
          v[q*4+0]+=u.x; v[q*4+1]+=u.y; v[q*4+2]+=u.z; v[q*4+3]+=u.w;
        }
      }
      const float4* pf = (const float4*)(featIn + base);
      #pragma unroll
      for (int q = 0; q < 4; ++q){
        float4 u = pf[q];
        v[q*4+0]+=u.x; v[q*4+1]+=u.y; v[q*4+2]+=u.z; v[q*4+3]+=u.w;
      }
    }
    float s = 0.f, sq = 0.f;
    #pragma unroll
    for (int j = 0; j < 16; ++j){ s += v[j]; sq += v[j]*v[j]; }
    float* redS = xcl; float* redQ = xcl + 544;   // moved out of Ws (prefetch target)
    redS[t*17 + ci] = s; redQ[t*17 + ci] = sq;
    __syncthreads();
    float S = 0.f, Q = 0.f;
    #pragma unroll
    for (int k2 = 0; k2 < 16; ++k2){ S += redS[t*17+k2]; Q += redQ[t*17+k2]; }
    float mu = S*(1.f/256.f), var = Q*(1.f/256.f) - mu*mu;
    float r = rsqrtf(var + 1e-5f);
    #pragma unroll
    for (int j = 0; j < 16; ++j){
      int c = ci*16 + j;
      v[j] = (v[j]-mu)*r*g[c] + bb[c];
      featT[c*36 + t] = v[j];
    }
    if (nt == 0){
      #pragma unroll
      for (int q = 0; q < 4; ++q){
        float4 o = {v[q*4+0], v[q*4+1], v[q*4+2], v[q*4+3]};
        *(float4*)&featOut[base + q*4] = o;
      }
    }
  }

  // ---- in_proj GEMM (r14 verified): wave-uniform X broadcast x stride-1 W ----
  int tg = tid >> 6, cc = tid & 63;
  float a0 = 0.f, a1 = 0.f, a2 = 0.f, a3 = 0.f;
  for (int kc = 0; kc < 4; ++kc){
    __syncthreads();
    if (kc == 0){
      // consume prefetched chunk 0 from registers
      int k = khP*8;
      Ws[(k+0)*68 + cP] = pW0.x; Ws[(k+1)*68 + cP] = pW0.y;
      Ws[(k+2)*68 + cP] = pW0.z; Ws[(k+3)*68 + cP] = pW0.w;
      Ws[(k+4)*68 + cP] = pW1.x; Ws[(k+5)*68 + cP] = pW1.y;
      Ws[(k+6)*68 + cP] = pW1.z; Ws[(k+7)*68 + cP] = pW1.w;
    } else {
      int c = tid >> 3, kh = tid & 7;
      const float4* src = (const float4*)(wip + (size_t)(n0+c)*DM + kc*64 + kh*8);
      #pragma unroll
      for (int q = 0; q < 2; ++q){
        float4 u = src[q];
        int k = kh*8 + q*4;
        Ws[(k+0)*68 + c] = u.x; Ws[(k+1)*68 + c] = u.y;
        Ws[(k+2)*68 + c] = u.z; Ws[(k+3)*68 + c] = u.w;
      }
    }
    __syncthreads();
    #pragma unroll 8
    for (int kk = 0; kk < 64; ++kk){
      vf4 xv = *(const vf4*)&featT[(kc*64 + kk)*36 + tg*4];  // broadcast
      float wv = Ws[kk*68 + cc];                             // stride-1
      a0 += xv[0]*wv; a1 += xv[1]*wv; a2 += xv[2]*wv; a3 += xv[3]*wv;
    }
  }
  __syncthreads();
  sxz[(tg*4+0)*65 + cc] = a0;
  sxz[(tg*4+1)*65 + cc] = a1;
  sxz[(tg*4+2)*65 + cc] = a2;
  sxz[(tg*4+3)*65 + cc] = a3;
  __syncthreads();

  { // conv+silu (x) / silu (z); coalesced float4 global stores (r14 verified)
    int t = tid >> 4, c4 = (tid & 15)*4;
    float rr[4];
    if (n0 < 512){
      #pragma unroll
      for (int j = 0; j < 4; ++j){
        int c = c4 + j, d = n0 + c;
        float4 k4 = *(const float4*)(cwl + (size_t)d*4);
        float a = cbl[d];
        if (t >= 3) a += k4.x*sxz[(t-3)*65 + c];
        if (t >= 2) a += k4.y*sxz[(t-2)*65 + c];
        if (t >= 1) a += k4.z*sxz[(t-1)*65 + c];
        a += k4.w*sxz[t*65 + c];
        rr[j] = silu_(a);
        xcl[t*65 + c] = rr[j];
      }
      float4 o = {rr[0], rr[1], rr[2], rr[3]};
      *(float4*)&xc[(size_t)(b*32 + t)*DI + n0 + c4] = o;
    } else {
      #pragma unroll
      for (int j = 0; j < 4; ++j) rr[j] = silu_(sxz[t*65 + c4 + j]);
      float4 o = {rr[0], rr[1], rr[2], rr[3]};
      *(float4*)&zs[(size_t)(b*32 + t)*DI + (n0 - 512) + c4] = o;
    }
  }
  if (n0 < 512){
    __syncthreads();
    int w = tid >> 6, ln = tid & 63;
    int tt = ln & 31, half = ln >> 5;
    #pragma unroll
    for (int j = 0; j < 6; ++j){
      int c = w*6 + j;
      const float* wr = xpl + (size_t)c*DI + n0 + half*32;
      const float* xr = xcl + tt*65 + half*32;
      float pa = 0.f;
      #pragma unroll 8
      for (int q = 0; q < 32; ++q) pa += wr[q]*xr[q];
      pa += __shfl_xor(pa, 32, 64);
      if (half == 0) pxp[((size_t)(b*8 + nt)*48 + c)*32 + tt] = pa;
    }
  }
}

// ---------- k_sc: xp-reduce + dt + scan + gate + out_proj -> parts[8] --------
// grid dim3(16 b, 8 ds of 64 d), 512 thr, static LDS ~75KB  (verified r14)
__global__ __launch_bounds__(512)
void k_sc(const float* __restrict__ pxp,
          const float* __restrict__ dtwl, const float* __restrict__ dtbl,
          const float* __restrict__ alogl, const float* __restrict__ dprl,
          const float* __restrict__ opwl,
          const float* __restrict__ xc, const float* __restrict__ zs,
          float* __restrict__ parts)
{
  __shared__ float sdtr[32*18], sB[32*18], sC[32*18];
  __shared__ float sdt[32*68], sxv[32*68], szz[32*68];
  __shared__ float ygT[64*36];
  __shared__ float Wop[32*260];
  int tid = threadIdx.x;
  int b = blockIdx.x, ds = blockIdx.y;   // XCD-local: linear%8 == b%8
  int d0 = ds*64;

  #pragma unroll
  for (int r = 0; r < 3; ++r){
    int o = r*512 + tid;
    int c = o >> 5, t = o & 31;
    size_t p0 = ((size_t)(b*8)*48 + c)*32 + t;
    float v = 0.f;
    #pragma unroll
    for (int nb = 0; nb < 8; ++nb) v += pxp[p0 + (size_t)nb*1536];
    if      (c < 16) sdtr[t*18 + c] = v;
    else if (c < 32) sB[t*18 + (c-16)] = v;
    else             sC[t*18 + (c-32)] = v;
  }
  {
    int t = tid >> 4, dq = (tid & 15)*4;
    size_t base = (size_t)(b*32 + t)*DI + d0 + dq;
    *(float4*)&sxv[t*68 + dq] = *(const float4*)&xc[base];
    *(float4*)&szz[t*68 + dq] = *(const float4*)&zs[base];
  }
  __syncthreads();
  {
    int dl = tid & 63, tg2 = tid >> 6;
    int d = d0 + dl;
    const float4* dwr = (const float4*)(dtwl + (size_t)d*16);
    float4 w0 = dwr[0], w1 = dwr[1], w2 = dwr[2], w3 = dwr[3];
    float bsv = dtbl[d];
    #pragma unroll
    for (int tt2 = 0; tt2 < 4; ++tt2){
      int t = tg2*4 + tt2;
      const float* sr = &sdtr[t*18];
      float a = bsv;
      a += w0.x*sr[0] + w0.y*sr[1] + w0.z*sr[2] + w0.w*sr[3];
      a += w1.x*sr[4] + w1.y*sr[5] + w1.z*sr[6] + w1.w*sr[7];
      a += w2.x*sr[8] + w2.y*sr[9] + w2.z*sr[10]+ w2.w*sr[11];
      a += w3.x*sr[12]+ w3.y*sr[13]+ w3.z*sr[14]+ w3.w*sr[15];
      sdt[t*68 + dl] = fmaxf(a, 0.f) + log1pf(expf(-fabsf(a)));
    }
  }
  __syncthreads();
  {
    int dd = tid >> 3, ng = tid & 7;
    int d = d0 + dd;
    int n0i = ng*2;
    float A0 = -expf(alogl[(size_t)d*16 + n0i]);
    float A1 = -expf(alogl[(size_t)d*16 + n0i + 1]);
    float Dp = dprl[d];
    float h0 = 0.f, h1 = 0.f;
    #pragma unroll 4
    for (int t = 0; t < TT; ++t){
      float dt = sdt[t*68 + dd];
      float xv = sxv[t*68 + dd];
      float dx = dt*xv;
      h0 = __expf(dt*A0)*h0 + dx*sB[t*18 + n0i];
      h1 = __expf(dt*A1)*h1 + dx*sB[t*18 + n0i + 1];
      float yv = h0*sC[t*18 + n0i] + h1*sC[t*18 + n0i + 1];
      yv += __shfl_xor(yv, 1, 64);
      yv += __shfl_xor(yv, 2, 64);
      yv += __shfl_xor(yv, 4, 64);
      if (ng == 0) ygT[dd*36 + t] = (yv + Dp*xv) * szz[t*68 + dd];
    }
  }
  int cW = tid >> 1, khW = tid & 1;
  int w = tid >> 6, cq = (tid & 63)*4;
  float acc[4][4] = {};
  for (int kc = 0; kc < 2; ++kc){
    __syncthreads();
    {
      const float4* src = (const float4*)(opwl + (size_t)cW*DI + d0 + kc*32 + khW*16);
      #pragma unroll
      for (int q = 0; q < 4; ++q){
        float4 u = src[q];
        int k = khW*16 + q*4;
        Wop[(k+0)*260 + cW] = u.x; Wop[(k+1)*260 + cW] = u.y;
        Wop[(k+2)*260 + cW] = u.z; Wop[(k+3)*260 + cW] = u.w;
      }
    }
    __syncthreads();
    #pragma unroll 4
    for (int k = 0; k < 32; ++k){
      vf4 xv = *(const vf4*)&ygT[(kc*32 + k)*36 + w*4];
      vf4 wv = *(const vf4*)&Wop[k*260 + cq];
      #pragma unroll
      for (int i = 0; i < 4; ++i){
        #pragma unroll
        for (int j = 0; j < 4; ++j) acc[i][j] += xv[i]*wv[j];
      }
    }
  }
  float* dst = parts + (size_t)ds*NTOK*DM;
  #pragma unroll
  for (int i = 0; i < 4; ++i){
    float4 o = {acc[i][0], acc[i][1], acc[i][2], acc[i][3]};
    *(float4*)&dst[(size_t)(b*32 + w*4 + i)*DM + cq] = o;
  }
}

// ---------- CLS: final residual+LN (token 31, 8 parts) + classifier ----------
__global__ __launch_bounds__(128)
void k_cls(const float* __restrict__ feat3, const float* __restrict__ parts,
           const float* __restrict__ ng, const float* __restrict__ nb,
           const float* __restrict__ w1, const float* __restrict__ b1,
           const float* __restrict__ w2, const float* __restrict__ b2,
           float* __restrict__ out)
{
  __shared__ float h[256];
  __shared__ float h1[128];
  int b = blockIdx.x, tid = threadIdx.x;
  if (tid < 64){
    int c4 = tid*4;
    size_t base = (size_t)(b*32 + 31)*DM + c4;
    float4 v = *(const float4*)&feat3[base];
    #pragma unroll
    for (int q = 0; q < 8; ++q){
      float4 u = *(const float4*)&parts[(size_t)q*NTOK*DM + base];
      v.x += u.x; v.y += u.y; v.z += u.z; v.w += u.w;
    }
    float sm = v.x+v.y+v.z+v.w;
    float sq = v.x*v.x+v.y*v.y+v.z*v.z+v.w*v.w;
    #pragma unroll
    for (int o = 1; o < 64; o <<= 1){ sm += __shfl_xor(sm, o, 64); sq += __shfl_xor(sq, o, 64); }
    float mu = sm*(1.f/256.f), var = sq*(1.f/256.f) - mu*mu;
    float r = rsqrtf(var + 1e-5f);
    h[c4+0] = (v.x-mu)*r*ng[c4+0] + nb[c4+0];
    h[c4+1] = (v.y-mu)*r*ng[c4+1] + nb[c4+1];
    h[c4+2] = (v.z-mu)*r*ng[c4+2] + nb[c4+2];
    h[c4+3] = (v.w-mu)*r*ng[c4+3] + nb[c4+3];
  }
  __syncthreads();
  {
    float a = b1[tid];
    const float* wr = w1 + (size_t)tid*256;
    #pragma unroll 8
    for (int j = 0; j < 256; ++j) a += h[j]*wr[j];
    h1[tid] = fmaxf(a, 0.f);
  }
  __syncthreads();
  if (tid < 2){
    float a2 = b2[tid];
    const float* wr2 = w2 + (size_t)tid*128;
    #pragma unroll 8
    for (int j = 0; j < 128; ++j) a2 += h1[j]*wr2[j];
    out[b*2 + tid] = a2;
  }
}

extern "C" void kernel_launch(void* const* d_in, const int* in_sizes, int n_in,
                              void* d_out, int out_size, void* d_ws, size_t ws_size,
                              hipStream_t stream)
{
  const float* x   = (const float*)d_in[0];
  const float* ep  = (const float*)d_in[1];
  const float* ef  = (const float*)d_in[2];
  const float* ed  = (const float*)d_in[3];
  const float* plw = (const float*)d_in[4];
  const float* plb = (const float*)d_in[5];
  const float* piw = (const float*)d_in[6];
  const float* pib = (const float*)d_in[7];
  const float* fw  = (const float*)d_in[8];
  const float* fb  = (const float*)d_in[9];
  const float* tg  = (const float*)d_in[10];
  const float* tb  = (const float*)d_in[11];
  const float* ng  = (const float*)d_in[12];
  const float* nb  = (const float*)d_in[13];
  const float* ipw = (const float*)d_in[14];
  const float* cw  = (const float*)d_in[15];
  const float* cb  = (const float*)d_in[16];
  const float* xpw = (const float*)d_in[17];
  const float* dtw = (const float*)d_in[18];
  const float* dtb = (const float*)d_in[19];
  const float* alog= (const float*)d_in[20];
  const float* dpr = (const float*)d_in[21];
  const float* opw = (const float*)d_in[22];
  const float* w1  = (const float*)d_in[23];
  const float* b1  = (const float*)d_in[24];
  const float* w2  = (const float*)d_in[25];
  const float* b2  = (const float*)d_in[26];
  (void)in_sizes; (void)n_in; (void)out_size; (void)ws_size;

  float* ws    = (float*)d_ws;
  float* s0    = ws;                       // 131072
  float* fb0   = s0  + NTOK*DM;            // 131072
  float* fb1   = fb0 + NTOK*DM;            // 131072
  float* parts = fb1 + NTOK*DM;            // 8*131072
  float* pxp   = parts + 8*NTOK*DM;        // 196608
  float* xc    = pxp + 196608;             // 262144
  float* zs    = xc  + NTOK*DI;            // 262144
  float* fbuf[2] = {fb0, fb1};

  k_front<<<dim3(16,4),128,0,stream>>>(x, ep,ef,ed, plw,plb,piw,pib, fw,fb, s0);

  for (int ly = 0; ly < 4; ++ly){
    const float* gg = ly ? ng : tg;
    const float* gb = ly ? nb : tb;
    const float* pin = ly ? parts : s0;
    const float* fin = ly ? fbuf[(ly+1)&1] : nullptr;
    k_A<<<dim3(16,16),512,70912,stream>>>(ipw + (size_t)ly*262144,
                                          cw + (size_t)ly*2048, cb + (size_t)ly*512,
                                          xpw + (size_t)ly*24576,
                                          gg, gb, pin, ly ? 1 : 0, fin,
                                          fbuf[ly&1], xc, zs, pxp);
    k_sc<<<dim3(16,8),512,0,stream>>>(pxp,
                                      dtw + (size_t)ly*8192, dtb + (size_t)ly*512,
                                      alog + (size_t)ly*8192, dpr + (size_t)ly*512,
                                      opw + (size_t)ly*131072,
                                      xc, zs, parts);
  }
  k_cls<<<16,128,0,stream>>>(fbuf[1], parts, ng, nb, w1, b1, w2, b2, (float*)d_out);
}